// Round 1
// baseline (500.010 us; speedup 1.0000x reference)
//
#include <hip/hip_runtime.h>
#include <math.h>

#pragma clang fp contract(off)

#define NPTS 4096
#define NC   20
#define NK   6
#define NM   3
#define NG   (NK*NM)
#define RES  48
#define NPIX (RES*RES)
#define NSAMP 16

// ---------------- kernel 1: projection, validity, top-2 features ----------------
__global__ void k_prep(const float* __restrict__ xyz, const float* __restrict__ feats,
                       const float* __restrict__ boxes, const float* __restrict__ theta,
                       const float* __restrict__ phi,
                       float* __restrict__ proj, float* __restrict__ top2,
                       unsigned char* __restrict__ valid) {
  int n = blockIdx.x * blockDim.x + threadIdx.x;
  if (n >= NPTS) return;
  float x = xyz[n*3+0], y = xyz[n*3+1], z = xyz[n*3+2];
  for (int m = 0; m < NM; ++m) {
    float th = theta[m], ph = phi[m];
    float st = (float)sin((double)th), ct = (float)cos((double)th);
    float sp = (float)sin((double)ph), cp = (float)cos((double)ph);
    float cx = ct*cp, cy = st*cp, cz = sp;          // center (r=1)
    float dx = x - cx, dy = y - cy, dz = z - cz;
    float u = dx*(-st) + dy*ct;                      // U = [-st, ct, 0]
    float v = (dx*(ct*sp) + dy*(st*sp)) + dz*cp;     // V = [ct*sp, st*sp, cp]
    proj[(m*NPTS+n)*2+0] = u;
    proj[(m*NPTS+n)*2+1] = v;
  }
  // top-2 of the 20 features (ascending sort [-2:]): m2 = 2nd largest, m1 = largest
  float m1 = -INFINITY, m2 = -INFINITY;
  for (int c = 0; c < NC; ++c) {
    float f = feats[n*NC+c];
    if (f > m1) { m2 = m1; m1 = f; }
    else if (f > m2) { m2 = f; }
  }
  top2[n*2+0] = m2;
  top2[n*2+1] = m1;
  for (int k = 0; k < NK; ++k) {
    const float* bx = boxes + k*6;
    bool v = (x >= bx[0]) && (y >= bx[1]) && (z >= bx[2]) &&
             (x <= bx[3]) && (y <= bx[4]) && (z <= bx[5]);
    valid[k*NPTS+n] = (unsigned char)(v ? 1 : 0);
  }
}

// ---------------- kernel 2: per-box count + coord-sum (deterministic tree) ----------------
__global__ void k_stats(const float* __restrict__ proj, const unsigned char* __restrict__ valid,
                        float* __restrict__ cnt, float* __restrict__ meanc) {
  int k = blockIdx.x, t = threadIdx.x;
  float pc = 0.f;
  float ps[NM][2] = {};
  for (int n = t; n < NPTS; n += 256) {
    if (valid[k*NPTS+n]) {
      pc += 1.f;
      for (int m = 0; m < NM; ++m) {
        ps[m][0] += proj[(m*NPTS+n)*2+0];
        ps[m][1] += proj[(m*NPTS+n)*2+1];
      }
    }
  }
  __shared__ float red[7][256];
  red[0][t] = pc;
  for (int m = 0; m < NM; ++m) { red[1+m*2][t] = ps[m][0]; red[2+m*2][t] = ps[m][1]; }
  __syncthreads();
  for (int s = 128; s > 0; s >>= 1) {
    if (t < s) for (int v2 = 0; v2 < 7; ++v2) red[v2][t] += red[v2][t+s];
    __syncthreads();
  }
  if (t == 0) {
    float c = red[0][0];
    cnt[k] = c;
    for (int m = 0; m < NM; ++m) {
      meanc[(k*NM+m)*2+0] = red[1+m*2][0] / c;
      meanc[(k*NM+m)*2+1] = red[2+m*2][0] / c;
    }
  }
}

// ---------------- kernel 3: per-(k,m) min/max -> center/scale ----------------
__global__ void k_minmax(const float* __restrict__ proj, const unsigned char* __restrict__ valid,
                         const float* __restrict__ cnt, const float* __restrict__ meanc,
                         float* __restrict__ cs) {
  int g = blockIdx.x; int k = g / NM, m = g % NM; int t = threadIdx.x;
  float mn0 = INFINITY, mn1 = INFINITY, mx0 = -INFINITY, mx1 = -INFINITY;
  for (int n = t; n < NPTS; n += 256) {
    if (valid[k*NPTS+n]) {
      float u = proj[(m*NPTS+n)*2+0], v = proj[(m*NPTS+n)*2+1];
      mn0 = fminf(mn0,u); mx0 = fmaxf(mx0,u);
      mn1 = fminf(mn1,v); mx1 = fmaxf(mx1,v);
    }
  }
  // invalid points carry mean_c coords; they participate in min/max
  if (cnt[k] < (float)NPTS) {
    float u = meanc[(k*NM+m)*2+0], v = meanc[(k*NM+m)*2+1];
    mn0 = fminf(mn0,u); mx0 = fmaxf(mx0,u);
    mn1 = fminf(mn1,v); mx1 = fmaxf(mx1,v);
  }
  __shared__ float r0[256], r1[256], r2[256], r3[256];
  r0[t]=mn0; r1[t]=mn1; r2[t]=mx0; r3[t]=mx1;
  __syncthreads();
  for (int s = 128; s > 0; s >>= 1) {
    if (t < s) {
      r0[t]=fminf(r0[t],r0[t+s]); r1[t]=fminf(r1[t],r1[t+s]);
      r2[t]=fmaxf(r2[t],r2[t+s]); r3[t]=fmaxf(r3[t],r3[t+s]);
    }
    __syncthreads();
  }
  if (t == 0) {
    float c0 = (r2[0]+r0[0]) / 2.0f;
    float c1 = (r3[0]+r1[0]) / 2.0f;
    float s0 = fmaxf(r2[0]-r0[0], 1e-5f) / 2.0f;
    float s1 = fmaxf(r3[0]-r1[0], 1e-5f) / 2.0f;
    cs[g*4+0]=c0; cs[g*4+1]=c1; cs[g*4+2]=s0; cs[g*4+3]=s1;
  }
}

// ---------------- kernel 4: per-pixel first-16 gather + softmax ----------------
__global__ void __launch_bounds__(256) k_main(const float* __restrict__ proj,
    const float* __restrict__ top2, const unsigned char* __restrict__ valid,
    const float* __restrict__ cs, float* __restrict__ out) {
  int tile = blockIdx.x, g = blockIdx.y;
  int k = g / NM, m = g % NM, t = threadIdx.x;
  __shared__ float2 lco[NPTS];   // normalized coords (invalid -> 1e30)
  __shared__ float2 lpt[NPTS];   // top-2 feature values
  float c0=cs[g*4+0], c1=cs[g*4+1], s0=cs[g*4+2], s1=cs[g*4+3];
  for (int n = t; n < NPTS; n += 256) {
    if (valid[k*NPTS+n]) {
      float u = proj[(m*NPTS+n)*2+0], v = proj[(m*NPTS+n)*2+1];
      // ((c - center)/scale + 1) * 0.8 * p / 2 + 0.1 * p   (p = 48), jax op order
      u = (u - c0) / s0; u = u + 1.0f; u = u * 0.8f; u = u * (float)RES; u = u / 2.0f; u = u + 0.1f*(float)RES;
      v = (v - c1) / s1; v = v + 1.0f; v = v * 0.8f; v = v * (float)RES; v = v / 2.0f; v = v + 0.1f*(float)RES;
      lco[n] = make_float2(u, v);
      lpt[n] = make_float2(top2[n*2+0], top2[n*2+1]);
    } else {
      lco[n] = make_float2(1e30f, 1e30f);
      lpt[n] = make_float2(0.f, 0.f);
    }
  }
  __syncthreads();
  int s = tile*256 + t;
  float si = (float)(s / RES), sj = (float)(s % RES);
  int hits = 0, occ0 = 0, occ1 = 0;
  float sum0 = 0.f, sum1 = 0.f;
  for (int n = 0; n < NPTS; ++n) {
    float2 co = lco[n];
    float dx = si - co.x, dy = sj - co.y;
    float d2 = dx*dx + dy*dy;
    if (d2 < 9.0f && hits < NSAMP) {
      float2 p = lpt[n];
      sum0 += p.x; sum1 += p.y;
      occ0 += (p.x != 0.f); occ1 += (p.y != 0.f);
      ++hits;
    }
    if ((n & 63) == 63 && __all(hits >= NSAMP)) break;
  }
  float o0 = occ0 == 0 ? 1.f : (float)occ0;
  float o1 = occ1 == 0 ? 1.f : (float)occ1;
  float nf0 = sum0 / o0, nf1 = sum1 / o1;
  float mxv = fmaxf(nf0, nf1);
  float e0 = expf(nf0 - mxv), e1 = expf(nf1 - mxv);
  float esum = e0 + e1;
  float a0 = e0 / esum, a1 = e1 / esum;
  float val = (a0 == a1) ? 0.f : a1 * 255.f;   // "empty" -> [1,0] -> channel1 = 0
  int i = s / RES, j = s % RES;
  int base = (g*3*RES + i)*RES + j;             // out[g][c][i][j]
  out[base] = val;
  out[base + NPIX] = val;
  out[base + 2*NPIX] = val;
}

extern "C" void kernel_launch(void* const* d_in, const int* in_sizes, int n_in,
                              void* d_out, int out_size, void* d_ws, size_t ws_size,
                              hipStream_t stream) {
  const float* xyz   = (const float*)d_in[0];
  const float* feats = (const float*)d_in[1];
  const float* boxes = (const float*)d_in[2];
  const float* theta = (const float*)d_in[3];
  const float* phi   = (const float*)d_in[4];
  // d_in[5] = res (assumed 48 per setup_inputs)
  float* out = (float*)d_out;

  char* ws = (char*)d_ws;
  float* proj = (float*)ws;                                  // M*N*2 floats
  float* top2 = proj + NM*NPTS*2;                            // N*2 floats
  unsigned char* valid = (unsigned char*)(top2 + NPTS*2);    // K*N bytes
  float* cnt = (float*)(valid + NK*NPTS);                    // K floats
  float* meanc = cnt + NK;                                   // K*M*2 floats
  float* cs = meanc + NK*NM*2;                               // G*4 floats

  k_prep<<<(NPTS+255)/256, 256, 0, stream>>>(xyz, feats, boxes, theta, phi, proj, top2, valid);
  k_stats<<<NK, 256, 0, stream>>>(proj, valid, cnt, meanc);
  k_minmax<<<NG, 256, 0, stream>>>(proj, valid, cnt, meanc, cs);
  k_main<<<dim3(NPIX/256, NG), 256, 0, stream>>>(proj, top2, valid, cs, out);
}

// Round 2
// 122.125 us; speedup vs baseline: 4.0942x; 4.0942x over previous
//
#include <hip/hip_runtime.h>
#include <math.h>

#pragma clang fp contract(off)

#define NPTS 4096
#define NC   20
#define NK   6
#define NM   3
#define NG   (NK*NM)
#define RES  48
#define NPIX (RES*RES)
#define NSAMP 16

// ---------------- kernel 1: trig + projection + validity + top-2 features ----------------
__global__ void k_prep(const float* __restrict__ xyz, const float* __restrict__ feats,
                       const float* __restrict__ boxes, const float* __restrict__ theta,
                       const float* __restrict__ phi,
                       float* __restrict__ proj, float* __restrict__ top2,
                       unsigned char* __restrict__ valid) {
  __shared__ float trig[NM][4];
  int t = threadIdx.x;
  if (t < NM) {
    double th = (double)theta[t], ph = (double)phi[t];
    trig[t][0] = (float)sin(th); trig[t][1] = (float)cos(th);
    trig[t][2] = (float)sin(ph); trig[t][3] = (float)cos(ph);
  }
  __syncthreads();
  int n = blockIdx.x * blockDim.x + t;
  if (n >= NPTS) return;
  float x = xyz[n*3+0], y = xyz[n*3+1], z = xyz[n*3+2];
  for (int m = 0; m < NM; ++m) {
    float st = trig[m][0], ct = trig[m][1], sp = trig[m][2], cp = trig[m][3];
    float cx = ct*cp, cy = st*cp, cz = sp;          // center (r=1)
    float dx = x - cx, dy = y - cy, dz = z - cz;
    float u = dx*(-st) + dy*ct;                      // U = [-st, ct, 0]
    float v = (dx*(ct*sp) + dy*(st*sp)) + dz*cp;     // V = [ct*sp, st*sp, cp]
    proj[(m*NPTS+n)*2+0] = u;
    proj[(m*NPTS+n)*2+1] = v;
  }
  float m1 = -INFINITY, m2 = -INFINITY;
  for (int c = 0; c < NC; ++c) {
    float f = feats[n*NC+c];
    if (f > m1) { m2 = m1; m1 = f; }
    else if (f > m2) { m2 = f; }
  }
  top2[n*2+0] = m2;
  top2[n*2+1] = m1;
  for (int k = 0; k < NK; ++k) {
    const float* bx = boxes + k*6;
    bool v = (x >= bx[0]) && (y >= bx[1]) && (z >= bx[2]) &&
             (x <= bx[3]) && (y <= bx[4]) && (z <= bx[5]);
    valid[k*NPTS+n] = (unsigned char)(v ? 1 : 0);
  }
}

// ---------------- kernel 2: per-(k,m) stats + minmax + center/scale + normalize ----------------
__global__ void k_box(const float* __restrict__ proj, const unsigned char* __restrict__ valid,
                      float* __restrict__ cs, float2* __restrict__ nco, int write_nco) {
  int g = blockIdx.x, k = g / NM, m = g % NM, t = threadIdx.x;
  __shared__ float red[4][256];
  __shared__ float bc[4];

  // phase 1: count + coord sums (tree order identical to r1's k_stats)
  float pc = 0.f, su = 0.f, sv = 0.f;
  for (int n = t; n < NPTS; n += 256) {
    if (valid[k*NPTS+n]) {
      pc += 1.f;
      su += proj[(m*NPTS+n)*2+0];
      sv += proj[(m*NPTS+n)*2+1];
    }
  }
  red[0][t] = pc; red[1][t] = su; red[2][t] = sv;
  __syncthreads();
  for (int s = 128; s > 0; s >>= 1) {
    if (t < s) { red[0][t]+=red[0][t+s]; red[1][t]+=red[1][t+s]; red[2][t]+=red[2][t+s]; }
    __syncthreads();
  }
  if (t == 0) {
    float c = red[0][0];
    bc[0] = c;
    bc[1] = red[1][0] / c;
    bc[2] = red[2][0] / c;
  }
  __syncthreads();
  float cnt = bc[0], mu = bc[1], mv = bc[2];
  __syncthreads();

  // phase 2: min/max over valid coords (+ mean coords if any invalid point exists)
  float mn0 = INFINITY, mn1 = INFINITY, mx0 = -INFINITY, mx1 = -INFINITY;
  for (int n = t; n < NPTS; n += 256) {
    if (valid[k*NPTS+n]) {
      float u = proj[(m*NPTS+n)*2+0], v = proj[(m*NPTS+n)*2+1];
      mn0 = fminf(mn0,u); mx0 = fmaxf(mx0,u);
      mn1 = fminf(mn1,v); mx1 = fmaxf(mx1,v);
    }
  }
  if (cnt < (float)NPTS) {
    mn0 = fminf(mn0,mu); mx0 = fmaxf(mx0,mu);
    mn1 = fminf(mn1,mv); mx1 = fmaxf(mx1,mv);
  }
  red[0][t]=mn0; red[1][t]=mn1; red[2][t]=mx0; red[3][t]=mx1;
  __syncthreads();
  for (int s = 128; s > 0; s >>= 1) {
    if (t < s) {
      red[0][t]=fminf(red[0][t],red[0][t+s]); red[1][t]=fminf(red[1][t],red[1][t+s]);
      red[2][t]=fmaxf(red[2][t],red[2][t+s]); red[3][t]=fmaxf(red[3][t],red[3][t+s]);
    }
    __syncthreads();
  }
  if (t == 0) {
    float c0 = (red[2][0]+red[0][0]) / 2.0f;
    float c1 = (red[3][0]+red[1][0]) / 2.0f;
    float s0 = fmaxf(red[2][0]-red[0][0], 1e-5f) / 2.0f;
    float s1 = fmaxf(red[3][0]-red[1][0], 1e-5f) / 2.0f;
    cs[g*4+0]=c0; cs[g*4+1]=c1; cs[g*4+2]=s0; cs[g*4+3]=s1;
    bc[0]=c0; bc[1]=c1; bc[2]=s0; bc[3]=s1;
  }
  __syncthreads();

  // phase 3: normalized coords per point (invalid -> 1e30), jax op order
  if (write_nco) {
    float c0=bc[0], c1=bc[1], s0=bc[2], s1=bc[3];
    for (int n = t; n < NPTS; n += 256) {
      float2 o;
      if (valid[k*NPTS+n]) {
        float u = proj[(m*NPTS+n)*2+0], v = proj[(m*NPTS+n)*2+1];
        u = (u - c0) / s0; u = u + 1.0f; u = u * 0.8f; u = u * (float)RES; u = u / 2.0f; u = u + 0.1f*(float)RES;
        v = (v - c1) / s1; v = v + 1.0f; v = v * 0.8f; v = v * (float)RES; v = v / 2.0f; v = v + 0.1f*(float)RES;
        o = make_float2(u, v);
      } else {
        o = make_float2(1e30f, 1e30f);
      }
      nco[g*NPTS+n] = o;
    }
  }
}

// ---------------- kernel 3: one wave per pixel, lanes parallel over points ----------------
template<bool FAST>
__global__ void __launch_bounds__(256) k_main(const float2* __restrict__ nco,
    const float* __restrict__ proj, const unsigned char* __restrict__ valid,
    const float* __restrict__ cs,
    const float2* __restrict__ pt2, float* __restrict__ out) {
  int wid  = (blockIdx.x * 256 + threadIdx.x) >> 6;   // global wave id == pixel id
  int lane = threadIdx.x & 63;
  int g = wid / NPIX, s = wid - g * NPIX;
  int k = g / NM, m = g - k * NM;
  float si = (float)(s / RES), sj = (float)(s % RES);

  float c0=0.f, c1=0.f, sc0=1.f, sc1=1.f;
  if (!FAST) { c0=cs[g*4+0]; c1=cs[g*4+1]; sc0=cs[g*4+2]; sc1=cs[g*4+3]; }

  float sum0 = 0.f, sum1 = 0.f, occ0 = 0.f, occ1 = 0.f;
  int hits = 0;

  const float2* con = nco + g * NPTS;

  float2 cur;
  if (FAST) cur = con[lane];          // prefetch chunk 0
  for (int base = 0; base < NPTS; base += 64) {
    float2 co;
    if (FAST) {
      co = cur;
      cur = con[base + 64 + lane];    // prefetch next (buffer padded by 64)
    } else {
      int n = base + lane;
      if (valid[k*NPTS+n]) {
        float u = proj[(m*NPTS+n)*2+0], v = proj[(m*NPTS+n)*2+1];
        u = (u - c0) / sc0; u = u + 1.0f; u = u * 0.8f; u = u * (float)RES; u = u / 2.0f; u = u + 0.1f*(float)RES;
        v = (v - c1) / sc1; v = v + 1.0f; v = v * 0.8f; v = v * (float)RES; v = v / 2.0f; v = v + 0.1f*(float)RES;
        co = make_float2(u, v);
      } else {
        co = make_float2(1e30f, 1e30f);
      }
    }
    float dx = si - co.x, dy = sj - co.y;
    float d2 = dx*dx + dy*dy;
    bool in = (d2 < 9.0f);
    unsigned long long mask = __ballot(in);
    if (mask) {
      unsigned long long below = mask & ((1ull << lane) - 1ull);
      int rank = __popcll(below);
      if (in && (hits + rank < NSAMP)) {
        float2 p = pt2[base + lane];
        sum0 += p.x; sum1 += p.y;
        occ0 += (p.x != 0.f) ? 1.f : 0.f;
        occ1 += (p.y != 0.f) ? 1.f : 0.f;
      }
      hits += __popcll(mask);
      if (hits >= NSAMP) break;
    }
  }

  // wave butterfly reduction
  for (int off = 32; off > 0; off >>= 1) {
    sum0 += __shfl_xor(sum0, off);
    sum1 += __shfl_xor(sum1, off);
    occ0 += __shfl_xor(occ0, off);
    occ1 += __shfl_xor(occ1, off);
  }

  if (lane == 0) {
    float o0 = (occ0 == 0.f) ? 1.f : occ0;
    float o1 = (occ1 == 0.f) ? 1.f : occ1;
    float nf0 = sum0 / o0, nf1 = sum1 / o1;
    float mxv = fmaxf(nf0, nf1);
    float e0 = expf(nf0 - mxv), e1 = expf(nf1 - mxv);
    float a1 = e1 / (e0 + e1);
    float val = (nf0 == nf1) ? 0.f : a1 * 255.f;   // empty -> [1,0] -> channel1 = 0
    int i = s / RES, j = s - (s / RES) * RES;
    int base2 = (g*3*RES + i)*RES + j;
    out[base2] = val;
    out[base2 + NPIX] = val;
    out[base2 + 2*NPIX] = val;
  }
}

extern "C" void kernel_launch(void* const* d_in, const int* in_sizes, int n_in,
                              void* d_out, int out_size, void* d_ws, size_t ws_size,
                              hipStream_t stream) {
  const float* xyz   = (const float*)d_in[0];
  const float* feats = (const float*)d_in[1];
  const float* boxes = (const float*)d_in[2];
  const float* theta = (const float*)d_in[3];
  const float* phi   = (const float*)d_in[4];
  float* out = (float*)d_out;

  // ws layout (bytes):
  //   proj : 0          .. 98304   (NM*NPTS*2 f32)
  //   top2 : 98304      .. 131072  (NPTS*2 f32)
  //   cs   : 131072     .. 131360  (NG*4 f32)
  //   valid: 131360     .. 155936  (NK*NPTS u8)
  //   nco  : 155936     .. 746272  ((NG*NPTS + 64) float2)
  char* ws = (char*)d_ws;
  float*          proj  = (float*)(ws);
  float*          top2  = (float*)(ws + 98304);
  float*          cs    = (float*)(ws + 131072);
  unsigned char*  valid = (unsigned char*)(ws + 131360);
  float2*         nco   = (float2*)(ws + 155936);
  const size_t need_fast = 155936 + (size_t)(NG*NPTS + 64) * sizeof(float2);
  int fast = (ws_size >= need_fast) ? 1 : 0;

  k_prep<<<NPTS/256, 256, 0, stream>>>(xyz, feats, boxes, theta, phi, proj, top2, valid);
  k_box<<<NG, 256, 0, stream>>>(proj, valid, cs, nco, fast);

  int nwaves = NG * NPIX;               // 41472
  int nblocks = nwaves * 64 / 256;      // 10368
  if (fast)
    k_main<true><<<nblocks, 256, 0, stream>>>(nco, proj, valid, cs, (const float2*)top2, out);
  else
    k_main<false><<<nblocks, 256, 0, stream>>>(nco, proj, valid, cs, (const float2*)top2, out);
}

// Round 3
// 75.238 us; speedup vs baseline: 6.6457x; 1.6232x over previous
//
#include <hip/hip_runtime.h>
#include <math.h>

#pragma clang fp contract(off)

#define NPTS 4096
#define NC   20
#define NK   6
#define NM   3
#define NG   (NK*NM)
#define RES  48
#define NPIX (RES*RES)
#define NSAMP 16
#define TS   8                       // tile side (pixels)
#define TPG  (RES/TS)                // 6 tiles per axis
#define NTIL (TPG*TPG)               // 36 tiles per g
#define NSL  4                       // point slices = waves per block
#define SLPTS (NPTS/NSL)             // 1024 points per slice

// ---------------- kernel 1: trig + projection + validity + top-2 features ----------------
__global__ void k_prep(const float* __restrict__ xyz, const float* __restrict__ feats,
                       const float* __restrict__ boxes, const float* __restrict__ theta,
                       const float* __restrict__ phi,
                       float* __restrict__ proj, float* __restrict__ top2,
                       unsigned char* __restrict__ valid) {
  __shared__ float trig[NM][4];
  int t = threadIdx.x;
  if (t < NM) {
    double th = (double)theta[t], ph = (double)phi[t];
    trig[t][0] = (float)sin(th); trig[t][1] = (float)cos(th);
    trig[t][2] = (float)sin(ph); trig[t][3] = (float)cos(ph);
  }
  __syncthreads();
  int n = blockIdx.x * blockDim.x + t;
  if (n >= NPTS) return;
  float x = xyz[n*3+0], y = xyz[n*3+1], z = xyz[n*3+2];
  for (int m = 0; m < NM; ++m) {
    float st = trig[m][0], ct = trig[m][1], sp = trig[m][2], cp = trig[m][3];
    float cx = ct*cp, cy = st*cp, cz = sp;          // center (r=1)
    float dx = x - cx, dy = y - cy, dz = z - cz;
    float u = dx*(-st) + dy*ct;                      // U = [-st, ct, 0]
    float v = (dx*(ct*sp) + dy*(st*sp)) + dz*cp;     // V = [ct*sp, st*sp, cp]
    proj[(m*NPTS+n)*2+0] = u;
    proj[(m*NPTS+n)*2+1] = v;
  }
  float m1 = -INFINITY, m2 = -INFINITY;
  for (int c = 0; c < NC; ++c) {
    float f = feats[n*NC+c];
    if (f > m1) { m2 = m1; m1 = f; }
    else if (f > m2) { m2 = f; }
  }
  top2[n*2+0] = m2;
  top2[n*2+1] = m1;
  for (int k = 0; k < NK; ++k) {
    const float* bx = boxes + k*6;
    bool v = (x >= bx[0]) && (y >= bx[1]) && (z >= bx[2]) &&
             (x <= bx[3]) && (y <= bx[4]) && (z <= bx[5]);
    valid[k*NPTS+n] = (unsigned char)(v ? 1 : 0);
  }
}

// ---------------- kernel 2: per-(k,m) stats + minmax + center/scale + normalize ----------------
__global__ void k_box(const float* __restrict__ proj, const unsigned char* __restrict__ valid,
                      float* __restrict__ cs, float2* __restrict__ nco, int write_nco) {
  int g = blockIdx.x, k = g / NM, m = g % NM, t = threadIdx.x;
  __shared__ float red[4][256];
  __shared__ float bc[4];

  float pc = 0.f, su = 0.f, sv = 0.f;
  for (int n = t; n < NPTS; n += 256) {
    if (valid[k*NPTS+n]) {
      pc += 1.f;
      su += proj[(m*NPTS+n)*2+0];
      sv += proj[(m*NPTS+n)*2+1];
    }
  }
  red[0][t] = pc; red[1][t] = su; red[2][t] = sv;
  __syncthreads();
  for (int s = 128; s > 0; s >>= 1) {
    if (t < s) { red[0][t]+=red[0][t+s]; red[1][t]+=red[1][t+s]; red[2][t]+=red[2][t+s]; }
    __syncthreads();
  }
  if (t == 0) {
    float c = red[0][0];
    bc[0] = c;
    bc[1] = red[1][0] / c;
    bc[2] = red[2][0] / c;
  }
  __syncthreads();
  float cnt = bc[0], mu = bc[1], mv = bc[2];
  __syncthreads();

  float mn0 = INFINITY, mn1 = INFINITY, mx0 = -INFINITY, mx1 = -INFINITY;
  for (int n = t; n < NPTS; n += 256) {
    if (valid[k*NPTS+n]) {
      float u = proj[(m*NPTS+n)*2+0], v = proj[(m*NPTS+n)*2+1];
      mn0 = fminf(mn0,u); mx0 = fmaxf(mx0,u);
      mn1 = fminf(mn1,v); mx1 = fmaxf(mx1,v);
    }
  }
  if (cnt < (float)NPTS) {
    mn0 = fminf(mn0,mu); mx0 = fmaxf(mx0,mu);
    mn1 = fminf(mn1,mv); mx1 = fmaxf(mx1,mv);
  }
  red[0][t]=mn0; red[1][t]=mn1; red[2][t]=mx0; red[3][t]=mx1;
  __syncthreads();
  for (int s = 128; s > 0; s >>= 1) {
    if (t < s) {
      red[0][t]=fminf(red[0][t],red[0][t+s]); red[1][t]=fminf(red[1][t],red[1][t+s]);
      red[2][t]=fmaxf(red[2][t],red[2][t+s]); red[3][t]=fmaxf(red[3][t],red[3][t+s]);
    }
    __syncthreads();
  }
  if (t == 0) {
    float c0 = (red[2][0]+red[0][0]) / 2.0f;
    float c1 = (red[3][0]+red[1][0]) / 2.0f;
    float s0 = fmaxf(red[2][0]-red[0][0], 1e-5f) / 2.0f;
    float s1 = fmaxf(red[3][0]-red[1][0], 1e-5f) / 2.0f;
    cs[g*4+0]=c0; cs[g*4+1]=c1; cs[g*4+2]=s0; cs[g*4+3]=s1;
    bc[0]=c0; bc[1]=c1; bc[2]=s0; bc[3]=s1;
  }
  __syncthreads();

  if (write_nco) {
    float c0=bc[0], c1=bc[1], s0=bc[2], s1=bc[3];
    for (int n = t; n < NPTS; n += 256) {
      float2 o;
      if (valid[k*NPTS+n]) {
        float u = proj[(m*NPTS+n)*2+0], v = proj[(m*NPTS+n)*2+1];
        u = (u - c0) / s0; u = u + 1.0f; u = u * 0.8f; u = u * (float)RES; u = u / 2.0f; u = u + 0.1f*(float)RES;
        v = (v - c1) / s1; v = v + 1.0f; v = v * 0.8f; v = v * (float)RES; v = v / 2.0f; v = v + 0.1f*(float)RES;
        o = make_float2(u, v);
      } else {
        o = make_float2(1e30f, 1e30f);
      }
      nco[g*NPTS+n] = o;
    }
  }
}

// ---------------- kernel 3: tile kernel — wave = 8x8 pixels, 4 point-slices ----------------
__global__ void __launch_bounds__(256) k_tile(const float2* __restrict__ nco,
    const float2* __restrict__ pt2, float* __restrict__ out) {
  int tile = blockIdx.x, g = blockIdx.y;
  int t = threadIdx.x, w = t >> 6, lane = t & 63;

  __shared__ float4 spts4[NPTS/2];                 // 32 KiB: all 4096 normalized coords
  __shared__ unsigned short sidx[NSL][64][NSAMP];  // 8 KiB: first-16 indices per slice per pixel
  __shared__ int scnt[NSL][64];                    // 1 KiB

  // stage coords (coalesced float4)
  {
    const float4* src = (const float4*)(nco + g*NPTS);
    for (int i = t; i < NPTS/2; i += 256) spts4[i] = src[i];
  }
  __syncthreads();

  int ti = tile / TPG, tj = tile - (tile / TPG) * TPG;
  float si = (float)(ti*TS + (lane >> 3));
  float sj = (float)(tj*TS + (lane & 7));

  int cnt = 0;
  int base0 = w * SLPTS;
  for (int c = 0; c < SLPTS/64; ++c) {             // 16 chunks of 64 points
    int base = base0 + c*64;
    #pragma unroll
    for (int half = 0; half < 2; ++half) {
      int hb = base + half*32;
      unsigned mask = 0;
      #pragma unroll
      for (int jj = 0; jj < 32; jj += 2) {
        float4 pq = spts4[(hb + jj) >> 1];         // 2 points, broadcast read
        float dx0 = si - pq.x, dy0 = sj - pq.y;
        float d20 = dx0*dx0 + dy0*dy0;
        mask = mask + mask + (d20 < 9.0f ? 1u : 0u);
        float dx1 = si - pq.z, dy1 = sj - pq.w;
        float d21 = dx1*dx1 + dy1*dy1;
        mask = mask + mask + (d21 < 9.0f ? 1u : 0u);
      }
      if (mask && cnt < NSAMP) {                   // rare, divergent
        unsigned mrev = __brev(mask);              // bit j <-> point hb+j
        do {
          int jj = __builtin_ctz(mrev);
          mrev &= mrev - 1u;
          sidx[w][lane][cnt] = (unsigned short)(hb + jj);
          ++cnt;
        } while (mrev && cnt < NSAMP);
      }
    }
    if (__all(cnt >= NSAMP)) break;                // per-wave (slice) early exit
  }
  scnt[w][lane] = cnt;
  __syncthreads();

  // merge: 4 lanes per pixel take ranks q, q+4, q+8, q+12 of the slice-ordered first-16
  int p = t >> 2, q = t & 3;
  int c0 = scnt[0][p], c1 = scnt[1][p], c2 = scnt[2][p], c3 = scnt[3][p];
  int t0 = min(c0, NSAMP);
  int t1 = min(t0 + c1, NSAMP);
  int t2 = min(t1 + c2, NSAMP);
  int t3 = min(t2 + c3, NSAMP);
  float sum0 = 0.f, sum1 = 0.f, occ0 = 0.f, occ1 = 0.f;
  for (int r = q; r < t3; r += 4) {
    int wsel, i2;
    if      (r < t0) { wsel = 0; i2 = r; }
    else if (r < t1) { wsel = 1; i2 = r - t0; }
    else if (r < t2) { wsel = 2; i2 = r - t1; }
    else             { wsel = 3; i2 = r - t2; }
    int n = sidx[wsel][p][i2];
    float2 f = pt2[n];
    sum0 += f.x; sum1 += f.y;
    occ0 += (f.x != 0.f) ? 1.f : 0.f;
    occ1 += (f.y != 0.f) ? 1.f : 0.f;
  }
  sum0 += __shfl_xor(sum0, 1); sum0 += __shfl_xor(sum0, 2);
  sum1 += __shfl_xor(sum1, 1); sum1 += __shfl_xor(sum1, 2);
  occ0 += __shfl_xor(occ0, 1); occ0 += __shfl_xor(occ0, 2);
  occ1 += __shfl_xor(occ1, 1); occ1 += __shfl_xor(occ1, 2);

  if (q == 0) {
    float o0 = (occ0 == 0.f) ? 1.f : occ0;
    float o1 = (occ1 == 0.f) ? 1.f : occ1;
    float nf0 = sum0 / o0, nf1 = sum1 / o1;
    float mxv = fmaxf(nf0, nf1);
    float e0 = expf(nf0 - mxv), e1 = expf(nf1 - mxv);
    float a1 = e1 / (e0 + e1);
    float val = (nf0 == nf1) ? 0.f : a1 * 255.f;   // empty -> [1,0] -> channel1 = 0
    int pi = ti*TS + (p >> 3), pj = tj*TS + (p & 7);
    int base2 = g*3*NPIX + pi*RES + pj;
    out[base2] = val;
    out[base2 + NPIX] = val;
    out[base2 + 2*NPIX] = val;
  }
}

// ---------------- fallback (small ws): wave-per-pixel, inline normalize ----------------
__global__ void __launch_bounds__(256) k_fallback(const float* __restrict__ proj,
    const unsigned char* __restrict__ valid, const float* __restrict__ cs,
    const float2* __restrict__ pt2, float* __restrict__ out) {
  int wid  = (blockIdx.x * 256 + threadIdx.x) >> 6;
  int lane = threadIdx.x & 63;
  int g = wid / NPIX, s = wid - g * NPIX;
  int k = g / NM, m = g - k * NM;
  float si = (float)(s / RES), sj = (float)(s % RES);
  float c0=cs[g*4+0], c1=cs[g*4+1], sc0=cs[g*4+2], sc1=cs[g*4+3];
  float sum0 = 0.f, sum1 = 0.f, occ0 = 0.f, occ1 = 0.f;
  int hits = 0;
  for (int base = 0; base < NPTS; base += 64) {
    int n = base + lane;
    float2 co;
    if (valid[k*NPTS+n]) {
      float u = proj[(m*NPTS+n)*2+0], v = proj[(m*NPTS+n)*2+1];
      u = (u - c0) / sc0; u = u + 1.0f; u = u * 0.8f; u = u * (float)RES; u = u / 2.0f; u = u + 0.1f*(float)RES;
      v = (v - c1) / sc1; v = v + 1.0f; v = v * 0.8f; v = v * (float)RES; v = v / 2.0f; v = v + 0.1f*(float)RES;
      co = make_float2(u, v);
    } else {
      co = make_float2(1e30f, 1e30f);
    }
    float dx = si - co.x, dy = sj - co.y;
    float d2 = dx*dx + dy*dy;
    bool in = (d2 < 9.0f);
    unsigned long long mask = __ballot(in);
    if (mask) {
      unsigned long long below = mask & ((1ull << lane) - 1ull);
      int rank = __popcll(below);
      if (in && (hits + rank < NSAMP)) {
        float2 pv = pt2[n];
        sum0 += pv.x; sum1 += pv.y;
        occ0 += (pv.x != 0.f) ? 1.f : 0.f;
        occ1 += (pv.y != 0.f) ? 1.f : 0.f;
      }
      hits += __popcll(mask);
      if (hits >= NSAMP) break;
    }
  }
  for (int off = 32; off > 0; off >>= 1) {
    sum0 += __shfl_xor(sum0, off);
    sum1 += __shfl_xor(sum1, off);
    occ0 += __shfl_xor(occ0, off);
    occ1 += __shfl_xor(occ1, off);
  }
  if (lane == 0) {
    float o0 = (occ0 == 0.f) ? 1.f : occ0;
    float o1 = (occ1 == 0.f) ? 1.f : occ1;
    float nf0 = sum0 / o0, nf1 = sum1 / o1;
    float mxv = fmaxf(nf0, nf1);
    float e0 = expf(nf0 - mxv), e1 = expf(nf1 - mxv);
    float a1 = e1 / (e0 + e1);
    float val = (nf0 == nf1) ? 0.f : a1 * 255.f;
    int i = s / RES, j = s - (s / RES) * RES;
    int base2 = (g*3*RES + i)*RES + j;
    out[base2] = val;
    out[base2 + NPIX] = val;
    out[base2 + 2*NPIX] = val;
  }
}

extern "C" void kernel_launch(void* const* d_in, const int* in_sizes, int n_in,
                              void* d_out, int out_size, void* d_ws, size_t ws_size,
                              hipStream_t stream) {
  const float* xyz   = (const float*)d_in[0];
  const float* feats = (const float*)d_in[1];
  const float* boxes = (const float*)d_in[2];
  const float* theta = (const float*)d_in[3];
  const float* phi   = (const float*)d_in[4];
  float* out = (float*)d_out;

  // ws layout (bytes):
  //   proj : 0          .. 98304   (NM*NPTS*2 f32)
  //   top2 : 98304      .. 131072  (NPTS*2 f32)
  //   cs   : 131072     .. 131360  (NG*4 f32)
  //   valid: 131360     .. 155936  (NK*NPTS u8)
  //   nco  : 155936     .. 746272  ((NG*NPTS + 64) float2)
  char* ws = (char*)d_ws;
  float*          proj  = (float*)(ws);
  float*          top2  = (float*)(ws + 98304);
  float*          cs    = (float*)(ws + 131072);
  unsigned char*  valid = (unsigned char*)(ws + 131360);
  float2*         nco   = (float2*)(ws + 155936);
  const size_t need_fast = 155936 + (size_t)(NG*NPTS + 64) * sizeof(float2);
  int fast = (ws_size >= need_fast) ? 1 : 0;

  k_prep<<<NPTS/256, 256, 0, stream>>>(xyz, feats, boxes, theta, phi, proj, top2, valid);
  k_box<<<NG, 256, 0, stream>>>(proj, valid, cs, nco, fast);

  if (fast) {
    k_tile<<<dim3(NTIL, NG), 256, 0, stream>>>(nco, (const float2*)top2, out);
  } else {
    int nblocks = NG * NPIX * 64 / 256;
    k_fallback<<<nblocks, 256, 0, stream>>>(proj, valid, cs, (const float2*)top2, out);
  }
}

// Round 4
// 24.815 us; speedup vs baseline: 20.1495x; 3.0320x over previous
//
#include <hip/hip_runtime.h>
#include <math.h>

#pragma clang fp contract(off)

#define NPTS 4096
#define NC   20
#define NK   6
#define NM   3
#define NG   (NK*NM)
#define RES  48
#define NPIX (RES*RES)
#define NSAMP 16
#define TS   8                       // tile side (pixels)
#define TPG  (RES/TS)                // 6 tiles per axis
#define NTIL (TPG*TPG)               // 36 tiles per g
#define NSL  8                       // point slices = waves per block
#define SLPTS (NPTS/NSL)             // 512 points per slice
#define BT   (NSL*64)                // 512 threads per tile block

// ---------------- fused kernel: projection+validity+box stats+normalize (+top2) --------
// Blocks 0..NG-1: per-(k,m) box pipeline. Reduction order is kept BIT-IDENTICAL to the
// round-2/3 k_box (256 threads, n = t + i*256 ascending, same trees) because cs/nco feed
// the d2<9 selection. Block NG: top-2 features.
__global__ void k_fused(const float* __restrict__ xyz, const float* __restrict__ feats,
                        const float* __restrict__ boxes, const float* __restrict__ theta,
                        const float* __restrict__ phi,
                        float* __restrict__ top2, float* __restrict__ cs,
                        float2* __restrict__ nco) {
  int g = blockIdx.x, t = threadIdx.x;
  if (g == NG) {
    for (int n = t; n < NPTS; n += 256) {
      float m1 = -INFINITY, m2 = -INFINITY;
      for (int c = 0; c < NC; ++c) {
        float f = feats[n*NC+c];
        if (f > m1) { m2 = m1; m1 = f; }
        else if (f > m2) { m2 = f; }
      }
      top2[n*2+0] = m2;
      top2[n*2+1] = m1;
    }
    return;
  }
  int k = g / NM, m = g % NM;
  __shared__ float trig[4];
  __shared__ float red[4][256];
  __shared__ float bc[4];
  if (t == 0) {
    double th = (double)theta[m], ph = (double)phi[m];
    trig[0] = (float)sin(th); trig[1] = (float)cos(th);
    trig[2] = (float)sin(ph); trig[3] = (float)cos(ph);
  }
  __syncthreads();
  float st = trig[0], ct = trig[1], sp = trig[2], cp = trig[3];
  float cxc = ct*cp, cyc = st*cp, czc = sp;
  float b0 = boxes[k*6+0], b1 = boxes[k*6+1], b2 = boxes[k*6+2];
  float b3 = boxes[k*6+3], b4 = boxes[k*6+4], b5 = boxes[k*6+5];

  float us[16], vs[16];
  unsigned vbits = 0;
  float pc = 0.f, su = 0.f, sv = 0.f;
  #pragma unroll
  for (int i = 0; i < 16; ++i) {
    int n = t + i*256;
    float x = xyz[n*3+0], y = xyz[n*3+1], z = xyz[n*3+2];
    float dx = x - cxc, dy = y - cyc, dz = z - czc;
    float u = dx*(-st) + dy*ct;                      // U = [-st, ct, 0]
    float v = (dx*(ct*sp) + dy*(st*sp)) + dz*cp;     // V = [ct*sp, st*sp, cp]
    us[i] = u; vs[i] = v;
    bool val = (x >= b0) && (y >= b1) && (z >= b2) &&
               (x <= b3) && (y <= b4) && (z <= b5);
    if (val) { vbits |= (1u << i); pc += 1.f; su += u; sv += v; }
  }
  red[0][t] = pc; red[1][t] = su; red[2][t] = sv;
  __syncthreads();
  for (int s = 128; s > 0; s >>= 1) {
    if (t < s) { red[0][t]+=red[0][t+s]; red[1][t]+=red[1][t+s]; red[2][t]+=red[2][t+s]; }
    __syncthreads();
  }
  if (t == 0) {
    float c = red[0][0];
    bc[0] = c;
    bc[1] = red[1][0] / c;
    bc[2] = red[2][0] / c;
  }
  __syncthreads();
  float cnt_ = bc[0], mu = bc[1], mv = bc[2];
  __syncthreads();

  float mn0 = INFINITY, mn1 = INFINITY, mx0 = -INFINITY, mx1 = -INFINITY;
  #pragma unroll
  for (int i = 0; i < 16; ++i) {
    if ((vbits >> i) & 1u) {
      mn0 = fminf(mn0,us[i]); mx0 = fmaxf(mx0,us[i]);
      mn1 = fminf(mn1,vs[i]); mx1 = fmaxf(mx1,vs[i]);
    }
  }
  if (cnt_ < (float)NPTS) {
    mn0 = fminf(mn0,mu); mx0 = fmaxf(mx0,mu);
    mn1 = fminf(mn1,mv); mx1 = fmaxf(mx1,mv);
  }
  red[0][t]=mn0; red[1][t]=mn1; red[2][t]=mx0; red[3][t]=mx1;
  __syncthreads();
  for (int s = 128; s > 0; s >>= 1) {
    if (t < s) {
      red[0][t]=fminf(red[0][t],red[0][t+s]); red[1][t]=fminf(red[1][t],red[1][t+s]);
      red[2][t]=fmaxf(red[2][t],red[2][t+s]); red[3][t]=fmaxf(red[3][t],red[3][t+s]);
    }
    __syncthreads();
  }
  if (t == 0) {
    float c0 = (red[2][0]+red[0][0]) / 2.0f;
    float c1 = (red[3][0]+red[1][0]) / 2.0f;
    float s0 = fmaxf(red[2][0]-red[0][0], 1e-5f) / 2.0f;
    float s1 = fmaxf(red[3][0]-red[1][0], 1e-5f) / 2.0f;
    cs[g*4+0]=c0; cs[g*4+1]=c1; cs[g*4+2]=s0; cs[g*4+3]=s1;
    bc[0]=c0; bc[1]=c1; bc[2]=s0; bc[3]=s1;
  }
  __syncthreads();
  float c0=bc[0], c1=bc[1], s0=bc[2], s1=bc[3];
  #pragma unroll
  for (int i = 0; i < 16; ++i) {
    int n = t + i*256;
    float2 o;
    if ((vbits >> i) & 1u) {
      float u = us[i], v = vs[i];
      u = (u - c0) / s0; u = u + 1.0f; u = u * 0.8f; u = u * (float)RES; u = u / 2.0f; u = u + 0.1f*(float)RES;
      v = (v - c1) / s1; v = v + 1.0f; v = v * 0.8f; v = v * (float)RES; v = v / 2.0f; v = v + 0.1f*(float)RES;
      o = make_float2(u, v);
    } else {
      o = make_float2(1e30f, 1e30f);
    }
    nco[g*NPTS+n] = o;
  }
}

// ---------------- tile kernel: wave = 8x8 pixels, halo cull, 8 point-slices ------------
__global__ void __launch_bounds__(BT) k_tile(const float2* __restrict__ nco,
    const float2* __restrict__ pt2, float* __restrict__ out) {
  int tile = blockIdx.x, g = blockIdx.y;
  int t = threadIdx.x, w = t >> 6, lane = t & 63;

  __shared__ float4 spts4[NPTS/2];                 // 32 KiB: all normalized coords
  __shared__ unsigned short sidx[NSL][64][NSAMP+1];// padded: no stride-32B bank pattern
  __shared__ unsigned char scnt[NSL][64];

  {
    const float4* src = (const float4*)(nco + g*NPTS);
    for (int i = t; i < NPTS/2; i += BT) spts4[i] = src[i];
  }
  __syncthreads();

  int ti = tile / TPG, tj = tile - (tile / TPG) * TPG;
  float si = (float)(ti*TS + (lane >> 3));
  float sj = (float)(tj*TS + (lane & 7));
  float lo0 = (float)(ti*TS) - 3.0f, hi0 = (float)(ti*TS + TS - 1) + 3.0f;
  float lo1 = (float)(tj*TS) - 3.0f, hi1 = (float)(tj*TS + TS - 1) + 3.0f;
  const float2* sp2 = (const float2*)spts4;

  int cnt = 0;
  int base0 = w * SLPTS;
  for (int c = 0; c < SLPTS/64; ++c) {             // 8 chunks of 64 points
    int base = base0 + c*64;
    float2 pl = sp2[base + lane];                  // lane's own point (cull test)
    bool cand = (pl.x >= lo0) && (pl.x <= hi0) && (pl.y >= lo1) && (pl.y <= hi1);
    unsigned long long msk = __ballot(cand);
    while (msk) {                                  // wave-uniform candidate walk, ascending
      int jj = __builtin_ctzll(msk);
      msk &= msk - 1ull;
      int n = base + jj;
      float2 pq = sp2[n];                          // broadcast read
      float dx = si - pq.x, dy = sj - pq.y;
      float d2 = dx*dx + dy*dy;
      if (d2 < 9.0f && cnt < NSAMP) {
        sidx[w][lane][cnt] = (unsigned short)n;
        ++cnt;
      }
    }
    if (__all(cnt >= NSAMP)) break;                // per-wave (slice) early exit
  }
  scnt[w][lane] = (unsigned char)cnt;
  __syncthreads();

  // merge: 8 lanes per pixel take ranks q, q+8, ... of the slice-ordered first-16
  int p = t >> 3, q = t & 7;
  int tt[NSL+1]; tt[0] = 0;
  #pragma unroll
  for (int ww = 0; ww < NSL; ++ww) {
    int s2 = tt[ww] + (int)scnt[ww][p];
    tt[ww+1] = s2 > NSAMP ? NSAMP : s2;
  }
  float sum0 = 0.f, sum1 = 0.f, occ0 = 0.f, occ1 = 0.f;
  for (int r = q; r < tt[NSL]; r += 8) {
    int wsel = 0, i2 = r;
    #pragma unroll
    for (int ww = 1; ww < NSL; ++ww) if (r >= tt[ww]) { wsel = ww; i2 = r - tt[ww]; }
    int n = sidx[wsel][p][i2];
    float2 f = pt2[n];
    sum0 += f.x; sum1 += f.y;
    occ0 += (f.x != 0.f) ? 1.f : 0.f;
    occ1 += (f.y != 0.f) ? 1.f : 0.f;
  }
  sum0 += __shfl_xor(sum0,1); sum0 += __shfl_xor(sum0,2); sum0 += __shfl_xor(sum0,4);
  sum1 += __shfl_xor(sum1,1); sum1 += __shfl_xor(sum1,2); sum1 += __shfl_xor(sum1,4);
  occ0 += __shfl_xor(occ0,1); occ0 += __shfl_xor(occ0,2); occ0 += __shfl_xor(occ0,4);
  occ1 += __shfl_xor(occ1,1); occ1 += __shfl_xor(occ1,2); occ1 += __shfl_xor(occ1,4);

  if (q == 0) {
    float o0 = (occ0 == 0.f) ? 1.f : occ0;
    float o1 = (occ1 == 0.f) ? 1.f : occ1;
    float nf0 = sum0 / o0, nf1 = sum1 / o1;
    float mxv = fmaxf(nf0, nf1);
    float e0 = expf(nf0 - mxv), e1 = expf(nf1 - mxv);
    float a1 = e1 / (e0 + e1);
    float val = (nf0 == nf1) ? 0.f : a1 * 255.f;   // empty -> [1,0] -> channel1 = 0
    int pi = ti*TS + (p >> 3), pj = tj*TS + (p & 7);
    int base2 = g*3*NPIX + pi*RES + pj;
    out[base2] = val;
    out[base2 + NPIX] = val;
    out[base2 + 2*NPIX] = val;
  }
}

// ======================= fallback path (ws too small) ==================================
__global__ void k_prep(const float* __restrict__ xyz, const float* __restrict__ feats,
                       const float* __restrict__ boxes, const float* __restrict__ theta,
                       const float* __restrict__ phi,
                       float* __restrict__ proj, float* __restrict__ top2,
                       unsigned char* __restrict__ valid) {
  __shared__ float trig[NM][4];
  int t = threadIdx.x;
  if (t < NM) {
    double th = (double)theta[t], ph = (double)phi[t];
    trig[t][0] = (float)sin(th); trig[t][1] = (float)cos(th);
    trig[t][2] = (float)sin(ph); trig[t][3] = (float)cos(ph);
  }
  __syncthreads();
  int n = blockIdx.x * blockDim.x + t;
  if (n >= NPTS) return;
  float x = xyz[n*3+0], y = xyz[n*3+1], z = xyz[n*3+2];
  for (int m = 0; m < NM; ++m) {
    float st = trig[m][0], ct = trig[m][1], sp = trig[m][2], cp = trig[m][3];
    float cx = ct*cp, cy = st*cp, cz = sp;
    float dx = x - cx, dy = y - cy, dz = z - cz;
    float u = dx*(-st) + dy*ct;
    float v = (dx*(ct*sp) + dy*(st*sp)) + dz*cp;
    proj[(m*NPTS+n)*2+0] = u;
    proj[(m*NPTS+n)*2+1] = v;
  }
  float m1 = -INFINITY, m2 = -INFINITY;
  for (int c = 0; c < NC; ++c) {
    float f = feats[n*NC+c];
    if (f > m1) { m2 = m1; m1 = f; }
    else if (f > m2) { m2 = f; }
  }
  top2[n*2+0] = m2;
  top2[n*2+1] = m1;
  for (int k = 0; k < NK; ++k) {
    const float* bx = boxes + k*6;
    bool v = (x >= bx[0]) && (y >= bx[1]) && (z >= bx[2]) &&
             (x <= bx[3]) && (y <= bx[4]) && (z <= bx[5]);
    valid[k*NPTS+n] = (unsigned char)(v ? 1 : 0);
  }
}

__global__ void k_box(const float* __restrict__ proj, const unsigned char* __restrict__ valid,
                      float* __restrict__ cs) {
  int g = blockIdx.x, k = g / NM, m = g % NM, t = threadIdx.x;
  __shared__ float red[4][256];
  __shared__ float bc[4];
  float pc = 0.f, su = 0.f, sv = 0.f;
  for (int n = t; n < NPTS; n += 256) {
    if (valid[k*NPTS+n]) {
      pc += 1.f;
      su += proj[(m*NPTS+n)*2+0];
      sv += proj[(m*NPTS+n)*2+1];
    }
  }
  red[0][t] = pc; red[1][t] = su; red[2][t] = sv;
  __syncthreads();
  for (int s = 128; s > 0; s >>= 1) {
    if (t < s) { red[0][t]+=red[0][t+s]; red[1][t]+=red[1][t+s]; red[2][t]+=red[2][t+s]; }
    __syncthreads();
  }
  if (t == 0) {
    float c = red[0][0];
    bc[0] = c; bc[1] = red[1][0] / c; bc[2] = red[2][0] / c;
  }
  __syncthreads();
  float cnt = bc[0], mu = bc[1], mv = bc[2];
  __syncthreads();
  float mn0 = INFINITY, mn1 = INFINITY, mx0 = -INFINITY, mx1 = -INFINITY;
  for (int n = t; n < NPTS; n += 256) {
    if (valid[k*NPTS+n]) {
      float u = proj[(m*NPTS+n)*2+0], v = proj[(m*NPTS+n)*2+1];
      mn0 = fminf(mn0,u); mx0 = fmaxf(mx0,u);
      mn1 = fminf(mn1,v); mx1 = fmaxf(mx1,v);
    }
  }
  if (cnt < (float)NPTS) {
    mn0 = fminf(mn0,mu); mx0 = fmaxf(mx0,mu);
    mn1 = fminf(mn1,mv); mx1 = fmaxf(mx1,mv);
  }
  red[0][t]=mn0; red[1][t]=mn1; red[2][t]=mx0; red[3][t]=mx1;
  __syncthreads();
  for (int s = 128; s > 0; s >>= 1) {
    if (t < s) {
      red[0][t]=fminf(red[0][t],red[0][t+s]); red[1][t]=fminf(red[1][t],red[1][t+s]);
      red[2][t]=fmaxf(red[2][t],red[2][t+s]); red[3][t]=fmaxf(red[3][t],red[3][t+s]);
    }
    __syncthreads();
  }
  if (t == 0) {
    cs[g*4+0]=(red[2][0]+red[0][0])/2.0f;
    cs[g*4+1]=(red[3][0]+red[1][0])/2.0f;
    cs[g*4+2]=fmaxf(red[2][0]-red[0][0],1e-5f)/2.0f;
    cs[g*4+3]=fmaxf(red[3][0]-red[1][0],1e-5f)/2.0f;
  }
}

__global__ void __launch_bounds__(256) k_fallback(const float* __restrict__ proj,
    const unsigned char* __restrict__ valid, const float* __restrict__ cs,
    const float2* __restrict__ pt2, float* __restrict__ out) {
  int wid  = (blockIdx.x * 256 + threadIdx.x) >> 6;
  int lane = threadIdx.x & 63;
  int g = wid / NPIX, s = wid - g * NPIX;
  int k = g / NM, m = g - k * NM;
  float si = (float)(s / RES), sj = (float)(s % RES);
  float c0=cs[g*4+0], c1=cs[g*4+1], sc0=cs[g*4+2], sc1=cs[g*4+3];
  float sum0 = 0.f, sum1 = 0.f, occ0 = 0.f, occ1 = 0.f;
  int hits = 0;
  for (int base = 0; base < NPTS; base += 64) {
    int n = base + lane;
    float2 co;
    if (valid[k*NPTS+n]) {
      float u = proj[(m*NPTS+n)*2+0], v = proj[(m*NPTS+n)*2+1];
      u = (u - c0) / sc0; u = u + 1.0f; u = u * 0.8f; u = u * (float)RES; u = u / 2.0f; u = u + 0.1f*(float)RES;
      v = (v - c1) / sc1; v = v + 1.0f; v = v * 0.8f; v = v * (float)RES; v = v / 2.0f; v = v + 0.1f*(float)RES;
      co = make_float2(u, v);
    } else {
      co = make_float2(1e30f, 1e30f);
    }
    float dx = si - co.x, dy = sj - co.y;
    float d2 = dx*dx + dy*dy;
    bool in = (d2 < 9.0f);
    unsigned long long mask = __ballot(in);
    if (mask) {
      unsigned long long below = mask & ((1ull << lane) - 1ull);
      int rank = __popcll(below);
      if (in && (hits + rank < NSAMP)) {
        float2 pv = pt2[n];
        sum0 += pv.x; sum1 += pv.y;
        occ0 += (pv.x != 0.f) ? 1.f : 0.f;
        occ1 += (pv.y != 0.f) ? 1.f : 0.f;
      }
      hits += __popcll(mask);
      if (hits >= NSAMP) break;
    }
  }
  for (int off = 32; off > 0; off >>= 1) {
    sum0 += __shfl_xor(sum0, off);
    sum1 += __shfl_xor(sum1, off);
    occ0 += __shfl_xor(occ0, off);
    occ1 += __shfl_xor(occ1, off);
  }
  if (lane == 0) {
    float o0 = (occ0 == 0.f) ? 1.f : occ0;
    float o1 = (occ1 == 0.f) ? 1.f : occ1;
    float nf0 = sum0 / o0, nf1 = sum1 / o1;
    float mxv = fmaxf(nf0, nf1);
    float e0 = expf(nf0 - mxv), e1 = expf(nf1 - mxv);
    float a1 = e1 / (e0 + e1);
    float val = (nf0 == nf1) ? 0.f : a1 * 255.f;
    int i = s / RES, j = s - (s / RES) * RES;
    int base2 = (g*3*RES + i)*RES + j;
    out[base2] = val;
    out[base2 + NPIX] = val;
    out[base2 + 2*NPIX] = val;
  }
}

extern "C" void kernel_launch(void* const* d_in, const int* in_sizes, int n_in,
                              void* d_out, int out_size, void* d_ws, size_t ws_size,
                              hipStream_t stream) {
  const float* xyz   = (const float*)d_in[0];
  const float* feats = (const float*)d_in[1];
  const float* boxes = (const float*)d_in[2];
  const float* theta = (const float*)d_in[3];
  const float* phi   = (const float*)d_in[4];
  float* out = (float*)d_out;

  // ws layout (bytes):
  //   proj : 0      .. 98304   (NM*NPTS*2 f32)   [fallback only]
  //   top2 : 98304  .. 131072  (NPTS*2 f32)
  //   cs   : 131072 .. 131360  (NG*4 f32)
  //   valid: 131360 .. 155936  (NK*NPTS u8)      [fallback only]
  //   nco  : 155936 .. 746272  ((NG*NPTS + 64) float2)
  char* ws = (char*)d_ws;
  float*          proj  = (float*)(ws);
  float*          top2  = (float*)(ws + 98304);
  float*          cs    = (float*)(ws + 131072);
  unsigned char*  valid = (unsigned char*)(ws + 131360);
  float2*         nco   = (float2*)(ws + 155936);
  const size_t need_fast = 155936 + (size_t)(NG*NPTS + 64) * sizeof(float2);
  int fast = (ws_size >= need_fast) ? 1 : 0;

  if (fast) {
    k_fused<<<NG+1, 256, 0, stream>>>(xyz, feats, boxes, theta, phi, top2, cs, nco);
    k_tile<<<dim3(NTIL, NG), BT, 0, stream>>>(nco, (const float2*)top2, out);
  } else {
    k_prep<<<NPTS/256, 256, 0, stream>>>(xyz, feats, boxes, theta, phi, proj, top2, valid);
    k_box<<<NG, 256, 0, stream>>>(proj, valid, cs);
    int nblocks = NG * NPIX * 64 / 256;
    k_fallback<<<nblocks, 256, 0, stream>>>(proj, valid, cs, (const float2*)top2, out);
  }
}